// Round 5
// baseline (102.609 us; speedup 1.0000x reference)
//
#include <hip/hip_runtime.h>
#include <math.h>

constexpr int N  = 20000;
constexpr int V  = 6;
constexpr int P  = 64;
constexpr int ND = 32;
constexpr float W_   = 1600.0f;
constexpr float H_   = 928.0f;
constexpr float EPS_ = 1e-5f;

typedef float    f32x2 __attribute__((ext_vector_type(2)));
typedef _Float16 h16x2 __attribute__((ext_vector_type(2)));

__device__ inline int   h2i(h16x2 h) { int i; __builtin_memcpy(&i, &h, 4); return i; }
__device__ inline h16x2 i2h(int i)   { h16x2 h; __builtin_memcpy(&h, &i, 4); return h; }

// One wave per TWO (n,v) pairs (lanes 0..31 = pair A depths, 32..63 = pair B).
// Phase 1: full-lane projection + coalesced nontemporal xy/mask stores
//          (arithmetic bit-identical to the passing round-1..3 kernels).
// Phase 2: CONSERVATIVE bbox prune in packed f16 (10 swizzles instead of 20):
//          outer bbox = packed min/max expanded by 2.0px (> f16 cvt error
//          bound of 0.5 ulp = 0.5px for values < 2048). Outer-box-inside-ROI
//          => exact hit; outer-box-disjoint => exact miss; else bit-exact
//          unrolled f32 fallback with +INF sentinels on invalid depths.
__global__ __launch_bounds__(256) void box_corr(
    const float* __restrict__ points,   // N x 3  [img_id, x, y]
    const float* __restrict__ trans,    // V x V x 4 x 4
    const float* __restrict__ rois,     // V x P x 4  [x1,y1,x2,y2]
    float* __restrict__ out_xy,         // N x V x ND x 2
    float* __restrict__ out_mask,       // N x V x ND
    float* __restrict__ out_corr)       // N x V x P
{
    const int gw   = __builtin_amdgcn_readfirstlane(
                        (int)((blockIdx.x * 256u + threadIdx.x) >> 6));
    const int lane = (int)(threadIdx.x & 63u);
    if (gw >= (N * V) / 2) return;

    const int pA = 2 * gw;
    const int pB = pA + 1;
    const int nA = pA / V, vA = pA - nA * V;
    const int nB = pB / V, vB = pB - nB * V;

    const float idA = points[nA * 3 + 0];
    const float xA  = points[nA * 3 + 1];
    const float yA  = points[nA * 3 + 2];
    const float idB = points[nB * 3 + 0];
    const float xB  = points[nB * 3 + 1];
    const float yB  = points[nB * 3 + 2];
    const int imgA = (int)idA;
    const int imgB = (int)idB;
    const int offA = (vA * V + imgA) * 16;
    const int offB = (vB * V + imgB) * 16;

    const bool hiHalf = lane >= 32;
    const int  dl     = lane & 31;
    const float x   = hiHalf ? xB : xA;
    const float y   = hiHalf ? yB : yA;
    const int   off = hiHalf ? offB : offA;

    // depths[k] = 0.5 + bin*k*(k+1), left-assoc f32 (matches jnp)
    const float k   = (float)dl;
    const float bin = (float)(69.5 / 1056.0);
    const float d   = __fadd_rn(0.5f, __fmul_rn(__fmul_rn(bin, k), __fadd_rn(k, 1.0f)));

    const float p0 = __fmul_rn(x, d);
    const float p1 = __fmul_rn(y, d);

    const float* T = trans + off;
    const float4 t0 = *(const float4*)(T + 0);
    const float4 t1 = *(const float4*)(T + 4);
    const float4 t2 = *(const float4*)(T + 8);
    // no FMA contraction: match numpy einsum's mul+add sequence
    const float r0 = __fadd_rn(__fadd_rn(__fadd_rn(__fmul_rn(t0.x, p0), __fmul_rn(t0.y, p1)), __fmul_rn(t0.z, d)), t0.w);
    const float r1 = __fadd_rn(__fadd_rn(__fadd_rn(__fmul_rn(t1.x, p0), __fmul_rn(t1.y, p1)), __fmul_rn(t1.z, d)), t1.w);
    const float r2 = __fadd_rn(__fadd_rn(__fadd_rn(__fmul_rn(t2.x, p0), __fmul_rn(t2.y, p1)), __fmul_rn(t2.z, d)), t2.w);

    const float zc = fmaxf(r2, EPS_);
    const float px = r0 / zc;   // IEEE divide — booleans must be exact
    const float py = r1 / zc;
    const bool  ok = (r2 > EPS_) && (px >= 0.0f) && (px < W_) && (py >= 0.0f) && (py < H_);

    // Streaming outputs: nontemporal, fully coalesced (gw*64+lane contiguous).
    const size_t base = (size_t)gw * 64 + lane;
    f32x2 xyv = { px, py };
    __builtin_nontemporal_store(xyv, ((f32x2*)out_xy) + base);
    __builtin_nontemporal_store(ok ? 1.0f : 0.0f, out_mask + base);

    const unsigned long long bal = __ballot(ok);

    float cA = 0.0f, cB = 0.0f;
    if (bal != 0ull) {
        const float4 ra = ((const float4*)rois)[vA * P + lane];
        const float4 rb = ((const float4*)rois)[vB * P + lane];

        // Sentinels: +INF (min side / exact fallback), -INF (max side).
        const float pxl = ok ? px : INFINITY;
        const float pyl = ok ? py : INFINITY;
        const float pxh = ok ? px : -INFINITY;
        const float pyh = ok ? py : -INFINITY;

        // Packed-f16 butterfly min/max per 32-lane half (xor masks <=16).
        h16x2 lov = { (_Float16)pxl, (_Float16)pyl };
        h16x2 hiv = { (_Float16)pxh, (_Float16)pyh };
        int lo = h2i(lov);
        int hi = h2i(hiv);
        #pragma unroll
        for (int m = 16; m >= 1; m >>= 1) {
            const int lo2 = __shfl_xor(lo, m, 64);
            const int hi2 = __shfl_xor(hi, m, 64);
            lo = h2i(__builtin_elementwise_min(i2h(lo), i2h(lo2)));
            hi = h2i(__builtin_elementwise_max(i2h(hi), i2h(hi2)));
        }
        const h16x2 loA = i2h(__builtin_amdgcn_readlane(lo, 0));
        const h16x2 hiA = i2h(__builtin_amdgcn_readlane(hi, 0));
        const h16x2 loB = i2h(__builtin_amdgcn_readlane(lo, 32));
        const h16x2 hiB = i2h(__builtin_amdgcn_readlane(hi, 32));

        // Outer (conservative) bboxes: f16 round-nearest err <= 0.5px here.
        const float AxL = (float)loA.x - 2.0f;
        const float AyL = (float)loA.y - 2.0f;
        const float AxH = (float)hiA.x + 2.0f;
        const float AyH = (float)hiA.y + 2.0f;
        const float BxL = (float)loB.x - 2.0f;
        const float ByL = (float)loB.y - 2.0f;
        const float BxH = (float)hiB.x + 2.0f;
        const float ByH = (float)hiB.y + 2.0f;

        const bool anyA = ((unsigned)bal) != 0u;
        const bool anyB = (bal >> 32) != 0ull;

        const int ipx = __float_as_int(pxl);
        const int ipy = __float_as_int(pyl);

        // ---- pair A ----
        {
            bool hit = anyA && (AxL > ra.x) && (AxH < ra.z) && (AyL > ra.y) && (AyH < ra.w);
            const bool disj = !anyA || !(AxH > ra.x) || !(AxL < ra.z) || !(AyH > ra.y) || !(AyL < ra.w);
            if (__ballot(!hit && !disj) != 0ull) {
                bool h = false;
                #pragma unroll
                for (int q = 0; q < 32; ++q) {
                    const float xd = __int_as_float(__builtin_amdgcn_readlane(ipx, q));
                    const float yd = __int_as_float(__builtin_amdgcn_readlane(ipy, q));
                    h = h || ((xd > ra.x) && (xd < ra.z) && (yd > ra.y) && (yd < ra.w));
                }
                hit = h;   // bit-exact for every lane (INF kills invalid depths)
            }
            cA = hit ? 1.0f : 0.0f;
        }
        // ---- pair B ----
        {
            bool hit = anyB && (BxL > rb.x) && (BxH < rb.z) && (ByL > rb.y) && (ByH < rb.w);
            const bool disj = !anyB || !(BxH > rb.x) || !(BxL < rb.z) || !(ByH > rb.y) || !(ByL < rb.w);
            if (__ballot(!hit && !disj) != 0ull) {
                bool h = false;
                #pragma unroll
                for (int q = 0; q < 32; ++q) {
                    const float xd = __int_as_float(__builtin_amdgcn_readlane(ipx, q + 32));
                    const float yd = __int_as_float(__builtin_amdgcn_readlane(ipy, q + 32));
                    h = h || ((xd > rb.x) && (xd < rb.z) && (yd > rb.y) && (yd < rb.w));
                }
                hit = h;
            }
            cB = hit ? 1.0f : 0.0f;
        }
    }

    __builtin_nontemporal_store(cA, out_corr + (size_t)pA * P + lane);
    __builtin_nontemporal_store(cB, out_corr + (size_t)pB * P + lane);
}

extern "C" void kernel_launch(void* const* d_in, const int* in_sizes, int n_in,
                              void* d_out, int out_size, void* d_ws, size_t ws_size,
                              hipStream_t stream) {
    const float* points = (const float*)d_in[0];   // 20000*3
    const float* trans  = (const float*)d_in[1];   // 6*6*4*4
    const float* rois   = (const float*)d_in[2];   // 6*64*4

    float* out      = (float*)d_out;
    float* out_xy   = out;                                   // N*V*ND*2
    float* out_mask = out + (size_t)N * V * ND * 2;          // N*V*ND
    float* out_corr = out_mask + (size_t)N * V * ND;         // N*V*P

    const int waves  = (N * V) / 2;      // 60000 waves, 2 pairs each
    const int blocks = (waves + 3) / 4;  // 4 waves / 256-thread block
    box_corr<<<blocks, 256, 0, stream>>>(points, trans, rois, out_xy, out_mask, out_corr);
}

// Round 6
// 101.078 us; speedup vs baseline: 1.0151x; 1.0151x over previous
//
#include <hip/hip_runtime.h>
#include <math.h>

constexpr int N  = 20000;
constexpr int V  = 6;
constexpr int P  = 64;
constexpr int ND = 32;
constexpr float W_   = 1600.0f;
constexpr float H_   = 928.0f;
constexpr float EPS_ = 1e-5f;

typedef float f32x2 __attribute__((ext_vector_type(2)));

// One wave per TWO (n,v) pairs (lanes 0..31 = pair A depths, 32..63 = pair B).
// Phase 1: full-lane projection + coalesced xy/mask stores (arithmetic
//          bit-identical to the passing round-1..3 kernels).
// Phase 2: EXACT f32 bbox prune (butterfly min/max over valid points, +INF
//          sentinels). bbox-inside-ROI => hit; bbox-disjoint => miss; else a
//          bit-exact fallback loop. Fallback broadcasts depth coords from LDS
//          (wave-uniform ds_read_b128, 2 depths per op, same-address
//          broadcast => conflict-free, DS pipe co-issues with VALU) instead
//          of per-depth v_readlane pairs.
__global__ __launch_bounds__(256) void box_corr(
    const float* __restrict__ points,   // N x 3  [img_id, x, y]
    const float* __restrict__ trans,    // V x V x 4 x 4
    const float* __restrict__ rois,     // V x P x 4  [x1,y1,x2,y2]
    float* __restrict__ out_xy,         // N x V x ND x 2
    float* __restrict__ out_mask,       // N x V x ND
    float* __restrict__ out_corr)       // N x V x P
{
    __shared__ float4 s_xy4[128];                 // 2 KB: (px,py) per thread
    float2* s_xy = (float2*)s_xy4;

    const int tid  = (int)threadIdx.x;
    const int gw   = __builtin_amdgcn_readfirstlane(
                        (int)((blockIdx.x * 256u + tid) >> 6));
    const int lane = tid & 63;
    if (gw >= (N * V) / 2) return;

    const int pA = 2 * gw;
    const int pB = pA + 1;
    const int nA = pA / V, vA = pA - nA * V;
    const int nB = pB / V, vB = pB - nB * V;

    const float idA = points[nA * 3 + 0];
    const float xA  = points[nA * 3 + 1];
    const float yA  = points[nA * 3 + 2];
    const float idB = points[nB * 3 + 0];
    const float xB  = points[nB * 3 + 1];
    const float yB  = points[nB * 3 + 2];
    const int imgA = (int)idA;
    const int imgB = (int)idB;
    const int offA = (vA * V + imgA) * 16;
    const int offB = (vB * V + imgB) * 16;

    const bool hiHalf = lane >= 32;
    const int  dl     = lane & 31;
    const float x   = hiHalf ? xB : xA;
    const float y   = hiHalf ? yB : yA;
    const int   off = hiHalf ? offB : offA;

    // depths[k] = 0.5 + bin*k*(k+1), left-assoc f32 (matches jnp)
    const float k   = (float)dl;
    const float bin = (float)(69.5 / 1056.0);
    const float d   = __fadd_rn(0.5f, __fmul_rn(__fmul_rn(bin, k), __fadd_rn(k, 1.0f)));

    const float p0 = __fmul_rn(x, d);
    const float p1 = __fmul_rn(y, d);

    const float* T = trans + off;
    const float4 t0 = *(const float4*)(T + 0);
    const float4 t1 = *(const float4*)(T + 4);
    const float4 t2 = *(const float4*)(T + 8);
    // no FMA contraction: match numpy einsum's mul+add sequence
    const float r0 = __fadd_rn(__fadd_rn(__fadd_rn(__fmul_rn(t0.x, p0), __fmul_rn(t0.y, p1)), __fmul_rn(t0.z, d)), t0.w);
    const float r1 = __fadd_rn(__fadd_rn(__fadd_rn(__fmul_rn(t1.x, p0), __fmul_rn(t1.y, p1)), __fmul_rn(t1.z, d)), t1.w);
    const float r2 = __fadd_rn(__fadd_rn(__fadd_rn(__fmul_rn(t2.x, p0), __fmul_rn(t2.y, p1)), __fmul_rn(t2.z, d)), t2.w);

    const float zc = fmaxf(r2, EPS_);
    const float px = r0 / zc;   // IEEE divide — booleans must be exact
    const float py = r1 / zc;
    const bool  ok = (r2 > EPS_) && (px >= 0.0f) && (px < W_) && (py >= 0.0f) && (py < H_);

    // Coalesced streaming stores (gw*64+lane contiguous).
    const size_t base = (size_t)gw * 64 + lane;
    ((f32x2*)out_xy)[base] = (f32x2){ px, py };
    out_mask[base] = ok ? 1.0f : 0.0f;

    const unsigned long long bal = __ballot(ok);

    float cA = 0.0f, cB = 0.0f;
    if (bal != 0ull) {
        // Sentinels: +INF for min-side & fallback (auto-fail box tests),
        // -INF for max-side.
        const float pxl = ok ? px : INFINITY;
        const float pyl = ok ? py : INFINITY;
        const float pxh = ok ? px : -INFINITY;
        const float pyh = ok ? py : -INFINITY;

        // Stage sentinel coords for the LDS-broadcast fallback (same-wave
        // write->read, no barrier needed; compiler inserts lgkmcnt wait).
        s_xy[tid] = make_float2(pxl, pyl);

        const float4 ra = ((const float4*)rois)[vA * P + lane];
        const float4 rb = ((const float4*)rois)[vB * P + lane];

        // Exact f32 butterfly min/max per 32-lane half (xor masks <=16).
        float xlo = pxl, ylo = pyl, xhi = pxh, yhi = pyh;
        #pragma unroll
        for (int m = 16; m >= 1; m >>= 1) {
            xlo = fminf(xlo, __shfl_xor(xlo, m, 64));
            xhi = fmaxf(xhi, __shfl_xor(xhi, m, 64));
            ylo = fminf(ylo, __shfl_xor(ylo, m, 64));
            yhi = fmaxf(yhi, __shfl_xor(yhi, m, 64));
        }
        const float AxL = __int_as_float(__builtin_amdgcn_readlane(__float_as_int(xlo), 0));
        const float AxH = __int_as_float(__builtin_amdgcn_readlane(__float_as_int(xhi), 0));
        const float AyL = __int_as_float(__builtin_amdgcn_readlane(__float_as_int(ylo), 0));
        const float AyH = __int_as_float(__builtin_amdgcn_readlane(__float_as_int(yhi), 0));
        const float BxL = __int_as_float(__builtin_amdgcn_readlane(__float_as_int(xlo), 32));
        const float BxH = __int_as_float(__builtin_amdgcn_readlane(__float_as_int(xhi), 32));
        const float ByL = __int_as_float(__builtin_amdgcn_readlane(__float_as_int(ylo), 32));
        const float ByH = __int_as_float(__builtin_amdgcn_readlane(__float_as_int(yhi), 32));

        const bool anyA = ((unsigned)bal) != 0u;
        const bool anyB = (bal >> 32) != 0ull;

        // Wave-uniform LDS base: this wave's 64 staged (px,py) entries.
        const float2* sbase = s_xy + (tid & ~63);

        // ---- pair A ----
        {
            bool hit = anyA && (AxL > ra.x) && (AxH < ra.z) && (AyL > ra.y) && (AyH < ra.w);
            const bool disj = !anyA || !(AxH > ra.x) || !(AxL < ra.z) || !(AyH > ra.y) || !(AyL < ra.w);
            if (__ballot(!hit && !disj) != 0ull) {
                bool h = false;
                #pragma unroll
                for (int q = 0; q < 32; q += 2) {   // 2 depths per ds_read_b128
                    const float4 v = *(const float4*)(sbase + q);
                    h = h || ((v.x > ra.x) && (v.x < ra.z) && (v.y > ra.y) && (v.y < ra.w));
                    h = h || ((v.z > ra.x) && (v.z < ra.z) && (v.w > ra.y) && (v.w < ra.w));
                }
                hit = h;   // bit-exact (INF sentinels kill invalid depths)
            }
            cA = hit ? 1.0f : 0.0f;
        }
        // ---- pair B ----
        {
            bool hit = anyB && (BxL > rb.x) && (BxH < rb.z) && (ByL > rb.y) && (ByH < rb.w);
            const bool disj = !anyB || !(BxH > rb.x) || !(BxL < rb.z) || !(ByH > rb.y) || !(ByL < rb.w);
            if (__ballot(!hit && !disj) != 0ull) {
                bool h = false;
                #pragma unroll
                for (int q = 0; q < 32; q += 2) {
                    const float4 v = *(const float4*)(sbase + 32 + q);
                    h = h || ((v.x > rb.x) && (v.x < rb.z) && (v.y > rb.y) && (v.y < rb.w));
                    h = h || ((v.z > rb.x) && (v.z < rb.z) && (v.w > rb.y) && (v.w < rb.w));
                }
                hit = h;
            }
            cB = hit ? 1.0f : 0.0f;
        }
    }

    out_corr[(size_t)pA * P + lane] = cA;
    out_corr[(size_t)pB * P + lane] = cB;
}

extern "C" void kernel_launch(void* const* d_in, const int* in_sizes, int n_in,
                              void* d_out, int out_size, void* d_ws, size_t ws_size,
                              hipStream_t stream) {
    const float* points = (const float*)d_in[0];   // 20000*3
    const float* trans  = (const float*)d_in[1];   // 6*6*4*4
    const float* rois   = (const float*)d_in[2];   // 6*64*4

    float* out      = (float*)d_out;
    float* out_xy   = out;                                   // N*V*ND*2
    float* out_mask = out + (size_t)N * V * ND * 2;          // N*V*ND
    float* out_corr = out_mask + (size_t)N * V * ND;         // N*V*P

    const int waves  = (N * V) / 2;      // 60000 waves, 2 pairs each
    const int blocks = (waves + 3) / 4;  // 4 waves / 256-thread block
    box_corr<<<blocks, 256, 0, stream>>>(points, trans, rois, out_xy, out_mask, out_corr);
}

// Round 7
// 97.766 us; speedup vs baseline: 1.0495x; 1.0339x over previous
//
#include <hip/hip_runtime.h>
#include <math.h>

constexpr int N  = 20000;
constexpr int V  = 6;
constexpr int P  = 64;
constexpr int ND = 32;
constexpr float W_   = 1600.0f;
constexpr float H_   = 928.0f;
constexpr float EPS_ = 1e-5f;

typedef float f32x2 __attribute__((ext_vector_type(2)));

// One wave per FOUR (n,v) pairs: 2 unrolled iterations x (lanes 0..31 = pair
// A depths, lanes 32..63 = pair B depths). The two iterations are fully
// independent (register-only phase 2), so the compiler can interleave
// iteration 1's loads/matvec/divides with iteration 0's butterfly/stores —
// attacking the latency-exposure gap (issue budget ~10us vs ~30us observed).
// Phase 1 arithmetic is bit-identical to the passing round-1..6 kernels.
// Phase 2: exact f32 bbox prune (butterfly min/max over valid points, +INF
// sentinels); bbox-inside-ROI => hit, bbox-disjoint => miss, else bit-exact
// readlane fallback over all 32 depths.
__global__ __launch_bounds__(256) void box_corr(
    const float* __restrict__ points,   // N x 3  [img_id, x, y]
    const float* __restrict__ trans,    // V x V x 4 x 4
    const float* __restrict__ rois,     // V x P x 4  [x1,y1,x2,y2]
    float* __restrict__ out_xy,         // N x V x ND x 2
    float* __restrict__ out_mask,       // N x V x ND
    float* __restrict__ out_corr)       // N x V x P
{
    const int tid  = (int)threadIdx.x;
    const int wid  = __builtin_amdgcn_readfirstlane(
                        (int)((blockIdx.x * 256u + tid) >> 6));
    const int lane = tid & 63;

    #pragma unroll
    for (int it = 0; it < 2; ++it) {
        const int gw = wid * 2 + it;           // < 60000 by grid construction

        const int pA = 2 * gw;
        const int pB = pA + 1;
        const int nA = pA / V, vA = pA - nA * V;
        const int nB = pB / V, vB = pB - nB * V;

        const float idA = points[nA * 3 + 0];
        const float xA  = points[nA * 3 + 1];
        const float yA  = points[nA * 3 + 2];
        const float idB = points[nB * 3 + 0];
        const float xB  = points[nB * 3 + 1];
        const float yB  = points[nB * 3 + 2];
        const int imgA = (int)idA;
        const int imgB = (int)idB;
        const int offA = (vA * V + imgA) * 16;
        const int offB = (vB * V + imgB) * 16;

        // Early ROI loads: independent of the matvec/divide chain (L1-hot).
        const float4 ra = ((const float4*)rois)[vA * P + lane];
        const float4 rb = ((const float4*)rois)[vB * P + lane];

        const bool hiHalf = lane >= 32;
        const int  dl     = lane & 31;
        const float x   = hiHalf ? xB : xA;
        const float y   = hiHalf ? yB : yA;
        const int   off = hiHalf ? offB : offA;

        // depths[k] = 0.5 + bin*k*(k+1), left-assoc f32 (matches jnp)
        const float k   = (float)dl;
        const float bin = (float)(69.5 / 1056.0);
        const float d   = __fadd_rn(0.5f, __fmul_rn(__fmul_rn(bin, k), __fadd_rn(k, 1.0f)));

        const float p0 = __fmul_rn(x, d);
        const float p1 = __fmul_rn(y, d);

        const float* T = trans + off;
        const float4 t0 = *(const float4*)(T + 0);
        const float4 t1 = *(const float4*)(T + 4);
        const float4 t2 = *(const float4*)(T + 8);
        // no FMA contraction: match numpy einsum's mul+add sequence
        const float r0 = __fadd_rn(__fadd_rn(__fadd_rn(__fmul_rn(t0.x, p0), __fmul_rn(t0.y, p1)), __fmul_rn(t0.z, d)), t0.w);
        const float r1 = __fadd_rn(__fadd_rn(__fadd_rn(__fmul_rn(t1.x, p0), __fmul_rn(t1.y, p1)), __fmul_rn(t1.z, d)), t1.w);
        const float r2 = __fadd_rn(__fadd_rn(__fadd_rn(__fmul_rn(t2.x, p0), __fmul_rn(t2.y, p1)), __fmul_rn(t2.z, d)), t2.w);

        const float zc = fmaxf(r2, EPS_);
        const float px = r0 / zc;   // IEEE divide — booleans must be exact
        const float py = r1 / zc;
        const bool  ok = (r2 > EPS_) && (px >= 0.0f) && (px < W_) && (py >= 0.0f) && (py < H_);

        // Coalesced streaming stores (gw*64+lane contiguous).
        const size_t base = (size_t)gw * 64 + lane;
        ((f32x2*)out_xy)[base] = (f32x2){ px, py };
        out_mask[base] = ok ? 1.0f : 0.0f;

        const unsigned long long bal = __ballot(ok);

        float cA = 0.0f, cB = 0.0f;
        if (bal != 0ull) {
            // Sentinels: +INF for min-side & fallback (auto-fail box tests),
            // -INF for max-side.
            const float pxl = ok ? px : INFINITY;
            const float pyl = ok ? py : INFINITY;
            const float pxh = ok ? px : -INFINITY;
            const float pyh = ok ? py : -INFINITY;

            // Exact f32 butterfly min/max per 32-lane half (xor masks <=16).
            float xlo = pxl, ylo = pyl, xhi = pxh, yhi = pyh;
            #pragma unroll
            for (int m = 16; m >= 1; m >>= 1) {
                xlo = fminf(xlo, __shfl_xor(xlo, m, 64));
                xhi = fmaxf(xhi, __shfl_xor(xhi, m, 64));
                ylo = fminf(ylo, __shfl_xor(ylo, m, 64));
                yhi = fmaxf(yhi, __shfl_xor(yhi, m, 64));
            }
            const float AxL = __int_as_float(__builtin_amdgcn_readlane(__float_as_int(xlo), 0));
            const float AxH = __int_as_float(__builtin_amdgcn_readlane(__float_as_int(xhi), 0));
            const float AyL = __int_as_float(__builtin_amdgcn_readlane(__float_as_int(ylo), 0));
            const float AyH = __int_as_float(__builtin_amdgcn_readlane(__float_as_int(yhi), 0));
            const float BxL = __int_as_float(__builtin_amdgcn_readlane(__float_as_int(xlo), 32));
            const float BxH = __int_as_float(__builtin_amdgcn_readlane(__float_as_int(xhi), 32));
            const float ByL = __int_as_float(__builtin_amdgcn_readlane(__float_as_int(ylo), 32));
            const float ByH = __int_as_float(__builtin_amdgcn_readlane(__float_as_int(yhi), 32));

            const bool anyA = ((unsigned)bal) != 0u;
            const bool anyB = (bal >> 32) != 0ull;

            const int ipx = __float_as_int(pxl);
            const int ipy = __float_as_int(pyl);

            // ---- pair A ----
            {
                bool hit = anyA && (AxL > ra.x) && (AxH < ra.z) && (AyL > ra.y) && (AyH < ra.w);
                const bool disj = !anyA || !(AxH > ra.x) || !(AxL < ra.z) || !(AyH > ra.y) || !(AyL < ra.w);
                if (__ballot(!hit && !disj) != 0ull) {
                    bool h = false;
                    #pragma unroll
                    for (int q = 0; q < 32; ++q) {
                        const float xd = __int_as_float(__builtin_amdgcn_readlane(ipx, q));
                        const float yd = __int_as_float(__builtin_amdgcn_readlane(ipy, q));
                        h = h || ((xd > ra.x) && (xd < ra.z) && (yd > ra.y) && (yd < ra.w));
                    }
                    hit = h;   // bit-exact (INF sentinels kill invalid depths)
                }
                cA = hit ? 1.0f : 0.0f;
            }
            // ---- pair B ----
            {
                bool hit = anyB && (BxL > rb.x) && (BxH < rb.z) && (ByL > rb.y) && (ByH < rb.w);
                const bool disj = !anyB || !(BxH > rb.x) || !(BxL < rb.z) || !(ByH > rb.y) || !(ByL < rb.w);
                if (__ballot(!hit && !disj) != 0ull) {
                    bool h = false;
                    #pragma unroll
                    for (int q = 0; q < 32; ++q) {
                        const float xd = __int_as_float(__builtin_amdgcn_readlane(ipx, q + 32));
                        const float yd = __int_as_float(__builtin_amdgcn_readlane(ipy, q + 32));
                        h = h || ((xd > rb.x) && (xd < rb.z) && (yd > rb.y) && (yd < rb.w));
                    }
                    hit = h;
                }
                cB = hit ? 1.0f : 0.0f;
            }
        }

        out_corr[(size_t)pA * P + lane] = cA;
        out_corr[(size_t)pB * P + lane] = cB;
    }
}

extern "C" void kernel_launch(void* const* d_in, const int* in_sizes, int n_in,
                              void* d_out, int out_size, void* d_ws, size_t ws_size,
                              hipStream_t stream) {
    const float* points = (const float*)d_in[0];   // 20000*3
    const float* trans  = (const float*)d_in[1];   // 6*6*4*4
    const float* rois   = (const float*)d_in[2];   // 6*64*4

    float* out      = (float*)d_out;
    float* out_xy   = out;                                   // N*V*ND*2
    float* out_mask = out + (size_t)N * V * ND * 2;          // N*V*ND
    float* out_corr = out_mask + (size_t)N * V * ND;         // N*V*P

    const int waves  = (N * V) / 4;      // 30000 waves, 4 pairs each (2 iters)
    const int blocks = (waves + 3) / 4;  // 4 waves / 256-thread block
    box_corr<<<blocks, 256, 0, stream>>>(points, trans, rois, out_xy, out_mask, out_corr);
}